// Round 9
// baseline (464.239 us; speedup 1.0000x reference)
//
#include <hip/hip_runtime.h>
#include <hip/hip_cooperative_groups.h>

namespace cg = cooperative_groups;

#define NN 2048
#define HALF 16777216ull              // B*N*N = 4*2048*2048
#define GRID 1024                     // 4 blocks/CU co-resident

typedef float  __attribute__((ext_vector_type(4))) f32x4;
typedef short  __attribute__((ext_vector_type(8))) s16x8;
typedef ushort __attribute__((ext_vector_type(4))) u16x4;

// fp32 -> bf16 (RTNE)
__device__ __forceinline__ ushort f2bf(float f) {
    union { float f; uint32_t u; } v; v.f = f;
    const uint32_t r = v.u + 0x7FFFu + ((v.u >> 16) & 1u);
    return (ushort)(r >> 16);
}

// block writes one idx row: idx[row][j] = (float)j
__device__ __forceinline__ void write_idx_row(float* __restrict__ out, int row, int t) {
    float* p = out + HALF + (size_t)row * NN + t * 8;
    const float c0 = (float)(t * 8);
    f32x4 v0 = {c0, c0 + 1.f, c0 + 2.f, c0 + 3.f};
    f32x4 v1 = {c0 + 4.f, c0 + 5.f, c0 + 6.f, c0 + 7.f};
    *(f32x4*)p = v0;
    *(f32x4*)(p + 4) = v1;
}

__global__ __launch_bounds__(256, 4) void coop_dgg(
    const float* __restrict__ x,
    const float* __restrict__ Wmu1, const float* __restrict__ bmu1,
    const float* __restrict__ Wmu2, const float* __restrict__ bmu2,
    const float* __restrict__ Wkp,  const float* __restrict__ bkp,
    ushort* __restrict__ w1t, ushort* __restrict__ w2t,
    float* __restrict__ shift, float* __restrict__ out)
{
    __shared__ ushort xs[16 * 136];   // x rows bf16
    __shared__ ushort h1[16 * 264];   // h1 rows bf16
    __shared__ float  red[4][16];

    cg::grid_group grid = cg::this_grid();
    const int bid = blockIdx.x, t = threadIdx.x;
    const int lane = t & 63, w = t >> 6;

    // ================= Phase A: weight transpose | idx rows 0..1279 =================
    if (bid < 384) {
        const int e = bid * 256 + t;              // 0..98303
        if (e < 32768) {
            const int k = e >> 8, n = e & 255;
            w1t[n * 128 + k] = f2bf(Wmu1[e]);
        } else {
            const int e2 = e - 32768;
            const int k = e2 >> 8, n = e2 & 255;
            w2t[n * 256 + k] = f2bf(Wmu2[e2]);
        }
    } else {
        const int r0 = (bid - 384) * 2;           // 0..1278
        write_idx_row(out, r0, t);
        write_idx_row(out, r0 + 1, t);
    }
    __threadfence();
    grid.sync();

    // ================= Phase B: MLP (512 blocks, 16 rows) | idx rows 1280..7935 =====
    if (bid < 512) {
        const int l16 = lane & 15, lq = lane >> 4;
        const int row0 = bid * 16;

        // stage x (16 rows x 128) -> bf16 LDS row-major
        {
            const int r = t >> 4, k0 = (t & 15) * 8;
            const float* src = x + (size_t)(row0 + r) * 128 + k0;
            s16x8 s;
            #pragma unroll
            for (int q = 0; q < 8; ++q) s[q] = (short)f2bf(src[q]);
            *(s16x8*)&xs[r * 136 + k0] = s;
        }
        __syncthreads();

        // layer 1: K=128 (4 chunks of 32)
        f32x4 acc[4] = {};
        #pragma unroll
        for (int kc = 0; kc < 4; ++kc) {
            const s16x8 b0 = *(const s16x8*)&xs[l16 * 136 + kc * 32 + lq * 8];
            #pragma unroll
            for (int nt = 0; nt < 4; ++nt) {
                const int ng = (w * 4 + nt) * 16 + l16;
                const s16x8 a = *(const s16x8*)(w1t + ng * 128 + kc * 32 + lq * 8);
                acc[nt] = __builtin_amdgcn_mfma_f32_16x16x32_bf16(a, b0, acc[nt], 0, 0, 0);
            }
        }

        // bias + relu -> h1 bf16 row-major [m][c]
        #pragma unroll
        for (int nt = 0; nt < 4; ++nt) {
            const int c0 = (w * 4 + nt) * 16 + lq * 4;
            const f32x4 bv = *(const f32x4*)&bmu1[c0];
            u16x4 hv;
            #pragma unroll
            for (int reg = 0; reg < 4; ++reg)
                hv[reg] = f2bf(fmaxf(acc[nt][reg] + bv[reg], 0.f));
            *(u16x4*)&h1[l16 * 264 + c0] = hv;
        }
        __syncthreads();

        // layer 2: K=256 (8 chunks of 32)
        f32x4 acc2[4] = {};
        #pragma unroll
        for (int kc = 0; kc < 8; ++kc) {
            const s16x8 b0 = *(const s16x8*)&h1[l16 * 264 + kc * 32 + lq * 8];
            #pragma unroll
            for (int nt = 0; nt < 4; ++nt) {
                const int ng = (w * 4 + nt) * 16 + l16;
                const s16x8 a = *(const s16x8*)(w2t + ng * 256 + kc * 32 + lq * 8);
                acc2[nt] = __builtin_amdgcn_mfma_f32_16x16x32_bf16(a, b0, acc2[nt], 0, 0, 0);
            }
        }

        // (h2 + b2) . wkp, reduce over lq groups, then across waves
        float p0 = 0.f;
        #pragma unroll
        for (int nt = 0; nt < 4; ++nt) {
            const int c0 = (w * 4 + nt) * 16 + lq * 4;
            const f32x4 b2 = *(const f32x4*)&bmu2[c0];
            const f32x4 wk = *(const f32x4*)&Wkp[c0];
            #pragma unroll
            for (int reg = 0; reg < 4; ++reg)
                p0 = fmaf(acc2[nt][reg] + b2[reg], wk[reg], p0);
        }
        p0 += __shfl_xor(p0, 16, 64);
        p0 += __shfl_xor(p0, 32, 64);
        if (lane < 16) red[w][lane] = p0;
        __syncthreads();
        if (t < 16) {
            const float s = red[0][t] + red[1][t] + red[2][t] + red[3][t];
            shift[row0 + t] = 7.0f * (s + bkp[0]) + 2.0f;   // fold +2 here
        }
    } else {
        const int r0 = 1280 + (bid - 512) * 13;   // 1280..7935
        #pragma unroll 4
        for (int rr = 0; rr < 13; ++rr)
            write_idx_row(out, r0 + rr, t);
    }
    __threadfence();
    grid.sync();

    // ================= Phase C: adj rows (8/block) + leftover idx ===================
    if (bid < 256) write_idx_row(out, 7936 + bid, t);   // rows 7936..8191

    // wave w handles rows bid*8 + w*2 + {0,1}
    #pragma unroll
    for (int rr = 0; rr < 2; ++rr) {
        const int row = bid * 8 + w * 2 + rr;
        const float s = shift[row];                       // includes the +2
        // exp needed only while s - 7*(i*256) > -20  =>  i < (s+20)/1792
        const int icut = min(8, max(0, (int)ceilf((s + 20.0f) * (1.0f / 1792.0f))));
        float* adj = out + (size_t)row * NN;
        for (int i = 0; i < 8; ++i) {
            const int c = i * 256 + lane * 4;
            f32x4 a = {0.f, 0.f, 0.f, 0.f};
            if (i < icut) {                               // wave-uniform branch
                #pragma unroll
                for (int q = 0; q < 4; ++q) {
                    const float z = fmaf(-7.0f, (float)(c + q), s);
                    a[q] = 1.0f / (1.0f + __expf(-z));
                }
            }
            *(f32x4*)(adj + c) = a;
        }
    }
}

extern "C" void kernel_launch(void* const* d_in, const int* in_sizes, int n_in,
                              void* d_out, int out_size, void* d_ws, size_t ws_size,
                              hipStream_t stream)
{
    (void)in_sizes; (void)n_in; (void)out_size; (void)ws_size;
    const float* x    = (const float*)d_in[0];
    // d_in[1..5] dead: softmax over size-1 axis == 1 -> edge_prob == 1/N exactly;
    // stable argsort of all-ties rows == identity permutation.
    const float* Wmu1 = (const float*)d_in[6];
    const float* bmu1 = (const float*)d_in[7];
    const float* Wmu2 = (const float*)d_in[8];
    const float* bmu2 = (const float*)d_in[9];
    const float* Wkp  = (const float*)d_in[10];
    const float* bkp  = (const float*)d_in[11];

    ushort* w1t   = (ushort*)d_ws;                          // 64 KB
    ushort* w2t   = (ushort*)((char*)d_ws + 65536);         // 128 KB
    float*  shift = (float*)((char*)d_ws + 65536 + 131072); // 32 KB
    float*  out   = (float*)d_out;

    void* args[] = { (void*)&x, (void*)&Wmu1, (void*)&bmu1, (void*)&Wmu2, (void*)&bmu2,
                     (void*)&Wkp, (void*)&bkp, (void*)&w1t, (void*)&w2t,
                     (void*)&shift, (void*)&out };
    hipLaunchCooperativeKernel((void*)coop_dgg, dim3(GRID), dim3(256), args, 0, stream);
}

// Round 10
// 40.069 us; speedup vs baseline: 11.5860x; 11.5860x over previous
//
#include <hip/hip_runtime.h>

#define NN 2048
#define HALF 16777216ull              // B*N*N = 4*2048*2048
#define MLPB 512                      // MLP blocks, 16 rows each
#define IDXB 2048                     // idx blocks, 4 rows each

typedef float  __attribute__((ext_vector_type(4))) f32x4;
typedef short  __attribute__((ext_vector_type(8))) s16x8;
typedef ushort __attribute__((ext_vector_type(4))) u16x4;

// fp32 -> bf16 (RTNE)
__device__ __forceinline__ ushort f2bf(float f) {
    union { float f; uint32_t u; } v; v.f = f;
    const uint32_t r = v.u + 0x7FFFu + ((v.u >> 16) & 1u);
    return (ushort)(r >> 16);
}

// ---------------- K1: weight transpose -> bf16 ----------------
// w1t[n*128+k] = bf16(Wmu1[k*256+n]);  w2t[n*256+k] = bf16(Wmu2[k*256+n])
__global__ __launch_bounds__(256) void k1_transpose(
    const float* __restrict__ Wmu1, const float* __restrict__ Wmu2,
    ushort* __restrict__ w1t, ushort* __restrict__ w2t)
{
    const int e = blockIdx.x * 256 + threadIdx.x;   // 0..98303
    if (e < 32768) {
        const int k = e >> 8, n = e & 255;
        w1t[n * 128 + k] = f2bf(Wmu1[e]);
    } else {
        const int e2 = e - 32768;
        const int k = e2 >> 8, n = e2 & 255;
        w2t[n * 256 + k] = f2bf(Wmu2[e2]);
    }
}

// ---------------- K2: {MFMA MLP (16 rows) + own adj rows} | {idx fill} ----------------
// blocks [0,512):     shift (LDS) for 16 rows, then adj[row][j] = sigmoid(s - 7j)
//                     (only first 256-col chunk needs exp; rest are exact-enough zeros)
// blocks [512,2560):  out[HALF + row*NN + j] = (float)j  (4 rows each)
__global__ __launch_bounds__(256) void k2_main(
    const float* __restrict__ x,
    const ushort* __restrict__ w1t, const float* __restrict__ bmu1,
    const ushort* __restrict__ w2t, const float* __restrict__ bmu2,
    const float* __restrict__ Wkp,  const float* __restrict__ bkp,
    float* __restrict__ out)
{
    __shared__ ushort xs[16 * 136];   // x rows bf16, stride 136
    __shared__ ushort h1[16 * 264];   // h1 rows bf16, stride 264
    __shared__ float  red[4][16];
    __shared__ float  sh_shift[16];

    const int bid = blockIdx.x, t = threadIdx.x;
    const int lane = t & 63, w = t >> 6;

    if (bid >= MLPB) {
        // ---- idx fill: pure streaming stores ----
        const int row = (bid - MLPB) * 4 + w;
        float* idx = out + HALF + (size_t)row * NN;
        #pragma unroll
        for (int i = 0; i < 8; ++i) {
            const int c = i * 256 + lane * 4;
            f32x4 v = {(float)c, (float)(c + 1), (float)(c + 2), (float)(c + 3)};
            *(f32x4*)(idx + c) = v;
        }
        return;
    }

    // ---- MFMA MLP path (math identical to rounds 6-9) ----
    const int l16 = lane & 15, lq = lane >> 4;
    const int row0 = bid * 16;

    // stage x (16 rows x 128 fp32) -> bf16 LDS row-major
    {
        const int r = t >> 4, k0 = (t & 15) * 8;
        const float* src = x + (size_t)(row0 + r) * 128 + k0;
        s16x8 s;
        #pragma unroll
        for (int q = 0; q < 8; ++q) s[q] = (short)f2bf(src[q]);
        *(s16x8*)&xs[r * 136 + k0] = s;
    }
    __syncthreads();

    // layer 1: K=128 (4 chunks of 32)
    f32x4 acc[4] = {};
    #pragma unroll
    for (int kc = 0; kc < 4; ++kc) {
        const s16x8 b0 = *(const s16x8*)&xs[l16 * 136 + kc * 32 + lq * 8];
        #pragma unroll
        for (int nt = 0; nt < 4; ++nt) {
            const int ng = (w * 4 + nt) * 16 + l16;
            const s16x8 a = *(const s16x8*)(w1t + ng * 128 + kc * 32 + lq * 8);
            acc[nt] = __builtin_amdgcn_mfma_f32_16x16x32_bf16(a, b0, acc[nt], 0, 0, 0);
        }
    }

    // bias + relu -> h1 bf16 row-major [m][c]
    #pragma unroll
    for (int nt = 0; nt < 4; ++nt) {
        const int c0 = (w * 4 + nt) * 16 + lq * 4;
        const f32x4 bv = *(const f32x4*)&bmu1[c0];
        u16x4 hv;
        #pragma unroll
        for (int reg = 0; reg < 4; ++reg)
            hv[reg] = f2bf(fmaxf(acc[nt][reg] + bv[reg], 0.f));
        *(u16x4*)&h1[l16 * 264 + c0] = hv;
    }
    __syncthreads();

    // layer 2: K=256 (8 chunks of 32)
    f32x4 acc2[4] = {};
    #pragma unroll
    for (int kc = 0; kc < 8; ++kc) {
        const s16x8 b0 = *(const s16x8*)&h1[l16 * 264 + kc * 32 + lq * 8];
        #pragma unroll
        for (int nt = 0; nt < 4; ++nt) {
            const int ng = (w * 4 + nt) * 16 + l16;
            const s16x8 a = *(const s16x8*)(w2t + ng * 256 + kc * 32 + lq * 8);
            acc2[nt] = __builtin_amdgcn_mfma_f32_16x16x32_bf16(a, b0, acc2[nt], 0, 0, 0);
        }
    }

    // (h2 + b2) . wkp, reduce within wave, then across waves
    float p0 = 0.f;
    #pragma unroll
    for (int nt = 0; nt < 4; ++nt) {
        const int c0 = (w * 4 + nt) * 16 + lq * 4;
        const f32x4 b2 = *(const f32x4*)&bmu2[c0];
        const f32x4 wk = *(const f32x4*)&Wkp[c0];
        #pragma unroll
        for (int reg = 0; reg < 4; ++reg)
            p0 = fmaf(acc2[nt][reg] + b2[reg], wk[reg], p0);
    }
    p0 += __shfl_xor(p0, 16, 64);
    p0 += __shfl_xor(p0, 32, 64);
    if (lane < 16) red[w][lane] = p0;
    __syncthreads();
    if (t < 16) {
        const float s = red[0][t] + red[1][t] + red[2][t] + red[3][t];
        sh_shift[t] = 7.0f * (s + bkp[0]) + 2.0f;   // fold the +2 here
    }
    __syncthreads();

    // ---- adj fill: wave w owns rows w*4..w*4+3 ----
    #pragma unroll
    for (int rr = 0; rr < 4; ++rr) {
        const int r = w * 4 + rr;
        const float s = sh_shift[r];
        // exp needed only while s - 1792*i > -20  =>  i < (s+20)/1792
        const int icut = min(8, max(0, (int)ceilf((s + 20.0f) * (1.0f / 1792.0f))));
        float* adj = out + (size_t)(row0 + r) * NN;
        for (int i = 0; i < 8; ++i) {
            const int c = i * 256 + lane * 4;
            f32x4 a = {0.f, 0.f, 0.f, 0.f};
            if (i < icut) {                          // wave-uniform branch
                #pragma unroll
                for (int q = 0; q < 4; ++q) {
                    const float z = fmaf(-7.0f, (float)(c + q), s);
                    a[q] = 1.0f / (1.0f + __expf(-z));
                }
            }
            *(f32x4*)(adj + c) = a;
        }
    }
}

extern "C" void kernel_launch(void* const* d_in, const int* in_sizes, int n_in,
                              void* d_out, int out_size, void* d_ws, size_t ws_size,
                              hipStream_t stream)
{
    (void)in_sizes; (void)n_in; (void)out_size; (void)ws_size;
    const float* x    = (const float*)d_in[0];
    // d_in[1..5] dead: softmax over size-1 axis == 1 -> edge_prob == 1/N exactly;
    // stable argsort of all-ties rows == identity permutation.
    const float* Wmu1 = (const float*)d_in[6];
    const float* bmu1 = (const float*)d_in[7];
    const float* Wmu2 = (const float*)d_in[8];
    const float* bmu2 = (const float*)d_in[9];
    const float* Wkp  = (const float*)d_in[10];
    const float* bkp  = (const float*)d_in[11];

    ushort* w1t = (ushort*)d_ws;                      // 64 KB  (256x128 bf16)
    ushort* w2t = (ushort*)((char*)d_ws + 65536);     // 128 KB (256x256 bf16)
    float*  out = (float*)d_out;

    hipLaunchKernelGGL(k1_transpose, dim3(384), dim3(256), 0, stream,
                       Wmu1, Wmu2, w1t, w2t);
    hipLaunchKernelGGL(k2_main, dim3(MLPB + IDXB), dim3(256), 0, stream,
                       x, w1t, bmu1, w2t, bmu2, Wkp, bkp, out);
}

// Round 11
// 39.341 us; speedup vs baseline: 11.8003x; 1.0185x over previous
//
#include <hip/hip_runtime.h>

#define NN 2048
#define HALF 16777216ull              // B*N*N = 4*2048*2048
#define MLPB 256                      // MLP blocks, 32 rows each

typedef float  __attribute__((ext_vector_type(4))) f32x4;
typedef short  __attribute__((ext_vector_type(8))) s16x8;
typedef ushort __attribute__((ext_vector_type(4))) u16x4;

// fp32 -> bf16 (RTNE)
__device__ __forceinline__ ushort f2bf(float f) {
    union { float f; uint32_t u; } v; v.f = f;
    const uint32_t r = v.u + 0x7FFFu + ((v.u >> 16) & 1u);
    return (ushort)(r >> 16);
}

// ---------------- K1: weight transpose (384 blocks) + idx half (2048 blocks) ----------------
// w1t[n*128+k] = bf16(Wmu1[k*256+n]);  w2t[n*256+k] = bf16(Wmu2[k*256+n])
// idx blocks: out[HALF + row*NN + j] = (float)j   (stable argsort of all-ties = identity)
__global__ __launch_bounds__(256) void k1_prep(
    const float* __restrict__ Wmu1, const float* __restrict__ Wmu2,
    ushort* __restrict__ w1t, ushort* __restrict__ w2t,
    float* __restrict__ out)
{
    const int bid = blockIdx.x, t = threadIdx.x;
    if (bid < 384) {
        const int e = bid * 256 + t;           // 0..98303
        if (e < 32768) {
            const int k = e >> 8, n = e & 255;
            w1t[n * 128 + k] = f2bf(Wmu1[e]);
        } else {
            const int e2 = e - 32768;
            const int k = e2 >> 8, n = e2 & 255;
            w2t[n * 256 + k] = f2bf(Wmu2[e2]);
        }
        return;
    }
    const int lane = t & 63, w = t >> 6;
    const int row = (bid - 384) * 4 + w;
    float* idx = out + HALF + (size_t)row * NN;
    #pragma unroll
    for (int i = 0; i < 8; ++i) {
        const int c = i * 256 + lane * 4;
        f32x4 v = {(float)c, (float)(c + 1), (float)(c + 2), (float)(c + 3)};
        *(f32x4*)(idx + c) = v;
    }
}

// ---------------- K2: MFMA MLP (32 rows/block) + adj half with icut ----------------
// shift (LDS) for 32 rows, then adj[row][j] = sigmoid(s - 7j); only the first
// 256-col chunk needs exp (s - 7j < -20 beyond it -> sigmoid == 0 exactly in fp32).
__global__ __launch_bounds__(256) void k2_main(
    const float* __restrict__ x,
    const ushort* __restrict__ w1t, const float* __restrict__ bmu1,
    const ushort* __restrict__ w2t, const float* __restrict__ bmu2,
    const float* __restrict__ Wkp,  const float* __restrict__ bkp,
    float* __restrict__ out)
{
    __shared__ ushort xs[32 * 136];   // x rows bf16, stride 136
    __shared__ ushort h1[32 * 264];   // h1 rows bf16, stride 264
    __shared__ float  red[4][2][16];
    __shared__ float  sh_shift[32];

    const int bid = blockIdx.x, t = threadIdx.x;
    const int lane = t & 63, w = t >> 6;
    const int l16 = lane & 15, lq = lane >> 4;
    const int row0 = bid * 32;

    // stage x (32 rows x 128 fp32) -> bf16 LDS row-major
    {
        const int r = t >> 3, k0 = (t & 7) * 16;
        const float* src = x + (size_t)(row0 + r) * 128 + k0;
        s16x8 s0, s1;
        #pragma unroll
        for (int q = 0; q < 8; ++q) {
            s0[q] = (short)f2bf(src[q]);
            s1[q] = (short)f2bf(src[8 + q]);
        }
        *(s16x8*)&xs[r * 136 + k0]     = s0;
        *(s16x8*)&xs[r * 136 + k0 + 8] = s1;
    }
    __syncthreads();

    // layer 1: K=128 (4 chunks of 32)
    f32x4 acc[2][4] = {};
    #pragma unroll
    for (int kc = 0; kc < 4; ++kc) {
        const s16x8 b0 = *(const s16x8*)&xs[l16 * 136 + kc * 32 + lq * 8];
        const s16x8 b1 = *(const s16x8*)&xs[(16 + l16) * 136 + kc * 32 + lq * 8];
        #pragma unroll
        for (int nt = 0; nt < 4; ++nt) {
            const int ng = (w * 4 + nt) * 16 + l16;
            const s16x8 a = *(const s16x8*)(w1t + ng * 128 + kc * 32 + lq * 8);
            acc[0][nt] = __builtin_amdgcn_mfma_f32_16x16x32_bf16(a, b0, acc[0][nt], 0, 0, 0);
            acc[1][nt] = __builtin_amdgcn_mfma_f32_16x16x32_bf16(a, b1, acc[1][nt], 0, 0, 0);
        }
    }

    // bias + relu -> h1 bf16 row-major
    #pragma unroll
    for (int nt = 0; nt < 4; ++nt) {
        const int c0 = (w * 4 + nt) * 16 + lq * 4;
        const f32x4 bv = *(const f32x4*)&bmu1[c0];
        #pragma unroll
        for (int mt = 0; mt < 2; ++mt) {
            u16x4 hv;
            #pragma unroll
            for (int reg = 0; reg < 4; ++reg)
                hv[reg] = f2bf(fmaxf(acc[mt][nt][reg] + bv[reg], 0.f));
            *(u16x4*)&h1[(mt * 16 + l16) * 264 + c0] = hv;
        }
    }
    __syncthreads();

    // layer 2: K=256 (8 chunks of 32)
    f32x4 acc2[2][4] = {};
    #pragma unroll
    for (int kc = 0; kc < 8; ++kc) {
        const s16x8 b0 = *(const s16x8*)&h1[l16 * 264 + kc * 32 + lq * 8];
        const s16x8 b1 = *(const s16x8*)&h1[(16 + l16) * 264 + kc * 32 + lq * 8];
        #pragma unroll
        for (int nt = 0; nt < 4; ++nt) {
            const int ng = (w * 4 + nt) * 16 + l16;
            const s16x8 a = *(const s16x8*)(w2t + ng * 256 + kc * 32 + lq * 8);
            acc2[0][nt] = __builtin_amdgcn_mfma_f32_16x16x32_bf16(a, b0, acc2[0][nt], 0, 0, 0);
            acc2[1][nt] = __builtin_amdgcn_mfma_f32_16x16x32_bf16(a, b1, acc2[1][nt], 0, 0, 0);
        }
    }

    // (h2 + b2) . wkp, reduce
    float p0 = 0.f, p1 = 0.f;
    #pragma unroll
    for (int nt = 0; nt < 4; ++nt) {
        const int c0 = (w * 4 + nt) * 16 + lq * 4;
        const f32x4 b2 = *(const f32x4*)&bmu2[c0];
        const f32x4 wk = *(const f32x4*)&Wkp[c0];
        #pragma unroll
        for (int reg = 0; reg < 4; ++reg) {
            p0 = fmaf(acc2[0][nt][reg] + b2[reg], wk[reg], p0);
            p1 = fmaf(acc2[1][nt][reg] + b2[reg], wk[reg], p1);
        }
    }
    p0 += __shfl_xor(p0, 16, 64);  p0 += __shfl_xor(p0, 32, 64);
    p1 += __shfl_xor(p1, 16, 64);  p1 += __shfl_xor(p1, 32, 64);
    if (lane < 16) { red[w][0][lane] = p0; red[w][1][lane] = p1; }
    __syncthreads();

    if (t < 32) {
        const int mt = t >> 4, m = t & 15;
        const float s = red[0][mt][m] + red[1][mt][m] + red[2][mt][m] + red[3][mt][m];
        sh_shift[t] = 7.0f * (s + bkp[0]) + 2.0f;   // fold the +2 here
    }
    __syncthreads();

    // ---- adj fill: wave w owns rows w*8..w*8+7; exp only below icut ----
    #pragma unroll 2
    for (int rr = 0; rr < 8; ++rr) {
        const int r = w * 8 + rr;
        const float s = sh_shift[r];
        // exp needed only while s - 1792*i > -20  =>  i < (s+20)/1792
        const int icut = min(8, max(0, (int)ceilf((s + 20.0f) * (1.0f / 1792.0f))));
        float* adj = out + (size_t)(row0 + r) * NN;
        for (int i = 0; i < 8; ++i) {
            const int c = i * 256 + lane * 4;
            f32x4 a = {0.f, 0.f, 0.f, 0.f};
            if (i < icut) {                          // wave-uniform branch
                #pragma unroll
                for (int q = 0; q < 4; ++q) {
                    const float z = fmaf(-7.0f, (float)(c + q), s);
                    a[q] = 1.0f / (1.0f + __expf(-z));
                }
            }
            *(f32x4*)(adj + c) = a;
        }
    }
}

extern "C" void kernel_launch(void* const* d_in, const int* in_sizes, int n_in,
                              void* d_out, int out_size, void* d_ws, size_t ws_size,
                              hipStream_t stream)
{
    (void)in_sizes; (void)n_in; (void)out_size; (void)ws_size;
    const float* x    = (const float*)d_in[0];
    // d_in[1..5] dead: softmax over size-1 axis == 1 -> edge_prob == 1/N exactly;
    // stable argsort of all-ties rows == identity permutation.
    const float* Wmu1 = (const float*)d_in[6];
    const float* bmu1 = (const float*)d_in[7];
    const float* Wmu2 = (const float*)d_in[8];
    const float* bmu2 = (const float*)d_in[9];
    const float* Wkp  = (const float*)d_in[10];
    const float* bkp  = (const float*)d_in[11];

    ushort* w1t = (ushort*)d_ws;                      // 64 KB  (256x128 bf16)
    ushort* w2t = (ushort*)((char*)d_ws + 65536);     // 128 KB (256x256 bf16)
    float*  out = (float*)d_out;

    hipLaunchKernelGGL(k1_prep, dim3(384 + 2048), dim3(256), 0, stream,
                       Wmu1, Wmu2, w1t, w2t, out);
    hipLaunchKernelGGL(k2_main, dim3(MLPB), dim3(256), 0, stream,
                       x, w1t, bmu1, w2t, bmu2, Wkp, bkp, out);
}

// Round 12
// 28.872 us; speedup vs baseline: 16.0794x; 1.3626x over previous
//
#include <hip/hip_runtime.h>

#define NN 2048
#define HALF 16777216ull              // B*N*N = 4*2048*2048
#define MLPB 256                      // MLP blocks, 32 rows each; idx blocks follow

typedef float  __attribute__((ext_vector_type(4))) f32x4;
typedef short  __attribute__((ext_vector_type(8))) s16x8;
typedef ushort __attribute__((ext_vector_type(4))) u16x4;

// fp32 -> bf16 (RTNE) — same bit-exact helper as all passing rounds
__device__ __forceinline__ ushort f2bf(float f) {
    union { float f; uint32_t u; } v; v.f = f;
    const uint32_t r = v.u + 0x7FFFu + ((v.u >> 16) & 1u);
    return (ushort)(r >> 16);
}

// Gather one MFMA A-fragment of W^T directly from fp32 W[k][n] (ldn = 256):
// lane needs W^T[ng][k0..k0+7] = W[k0+j][ng]. Values bit-identical to the old
// pre-transposed w1t/w2t path (same f2bf), so absmax is unchanged.
__device__ __forceinline__ s16x8 gatherW(const float* __restrict__ W, int ng, int k0) {
    s16x8 a;
    #pragma unroll
    for (int j = 0; j < 8; ++j)
        a[j] = (short)f2bf(W[(k0 + j) * 256 + ng]);
    return a;
}

// ---------------- single kernel: {MFMA MLP + icut adj} | {idx fill} ----------------
// blocks [0,256):     32 rows each: shift (LDS), then adj[row][j] = sigmoid(s-7j);
//                     only the first 256-col chunk needs exp (z < -20 beyond it).
// blocks [256,2304):  out[HALF + row*NN + j] = (float)j  (4 rows each)
__global__ __launch_bounds__(256) void dgg_all(
    const float* __restrict__ x,
    const float* __restrict__ Wmu1, const float* __restrict__ bmu1,
    const float* __restrict__ Wmu2, const float* __restrict__ bmu2,
    const float* __restrict__ Wkp,  const float* __restrict__ bkp,
    float* __restrict__ out)
{
    __shared__ ushort xs[32 * 136];   // x rows bf16, stride 136
    __shared__ ushort h1[32 * 264];   // h1 rows bf16, stride 264
    __shared__ float  red[4][2][16];
    __shared__ float  sh_shift[32];

    const int bid = blockIdx.x, t = threadIdx.x;
    const int lane = t & 63, w = t >> 6;

    if (bid >= MLPB) {
        // ---- idx fill: pure streaming stores ----
        const int row = (bid - MLPB) * 4 + w;
        float* idx = out + HALF + (size_t)row * NN;
        #pragma unroll
        for (int i = 0; i < 8; ++i) {
            const int c = i * 256 + lane * 4;
            f32x4 v = {(float)c, (float)(c + 1), (float)(c + 2), (float)(c + 3)};
            *(f32x4*)(idx + c) = v;
        }
        return;
    }

    // ---- MFMA MLP path (math identical to rounds 6-11; A-frags gathered) ----
    const int l16 = lane & 15, lq = lane >> 4;
    const int row0 = bid * 32;
    const int k0l = lq * 8;           // this lane's k-offset within a 32-chunk

    // stage x (32 rows x 128 fp32) -> bf16 LDS row-major
    {
        const int r = t >> 3, k0 = (t & 7) * 16;
        const float* src = x + (size_t)(row0 + r) * 128 + k0;
        s16x8 s0, s1;
        #pragma unroll
        for (int q = 0; q < 8; ++q) {
            s0[q] = (short)f2bf(src[q]);
            s1[q] = (short)f2bf(src[8 + q]);
        }
        *(s16x8*)&xs[r * 136 + k0]     = s0;
        *(s16x8*)&xs[r * 136 + k0 + 8] = s1;
    }
    __syncthreads();

    // layer 1: K=128 (4 chunks of 32)
    f32x4 acc[2][4] = {};
    #pragma unroll
    for (int kc = 0; kc < 4; ++kc) {
        const s16x8 b0 = *(const s16x8*)&xs[l16 * 136 + kc * 32 + k0l];
        const s16x8 b1 = *(const s16x8*)&xs[(16 + l16) * 136 + kc * 32 + k0l];
        #pragma unroll
        for (int nt = 0; nt < 4; ++nt) {
            const int ng = (w * 4 + nt) * 16 + l16;
            const s16x8 a = gatherW(Wmu1, ng, kc * 32 + k0l);
            acc[0][nt] = __builtin_amdgcn_mfma_f32_16x16x32_bf16(a, b0, acc[0][nt], 0, 0, 0);
            acc[1][nt] = __builtin_amdgcn_mfma_f32_16x16x32_bf16(a, b1, acc[1][nt], 0, 0, 0);
        }
    }

    // bias + relu -> h1 bf16 row-major
    #pragma unroll
    for (int nt = 0; nt < 4; ++nt) {
        const int c0 = (w * 4 + nt) * 16 + lq * 4;
        const f32x4 bv = *(const f32x4*)&bmu1[c0];
        #pragma unroll
        for (int mt = 0; mt < 2; ++mt) {
            u16x4 hv;
            #pragma unroll
            for (int reg = 0; reg < 4; ++reg)
                hv[reg] = f2bf(fmaxf(acc[mt][nt][reg] + bv[reg], 0.f));
            *(u16x4*)&h1[(mt * 16 + l16) * 264 + c0] = hv;
        }
    }
    __syncthreads();

    // layer 2: K=256 (8 chunks of 32)
    f32x4 acc2[2][4] = {};
    #pragma unroll
    for (int kc = 0; kc < 8; ++kc) {
        const s16x8 b0 = *(const s16x8*)&h1[l16 * 264 + kc * 32 + k0l];
        const s16x8 b1 = *(const s16x8*)&h1[(16 + l16) * 264 + kc * 32 + k0l];
        #pragma unroll
        for (int nt = 0; nt < 4; ++nt) {
            const int ng = (w * 4 + nt) * 16 + l16;
            const s16x8 a = gatherW(Wmu2, ng, kc * 32 + k0l);
            acc2[0][nt] = __builtin_amdgcn_mfma_f32_16x16x32_bf16(a, b0, acc2[0][nt], 0, 0, 0);
            acc2[1][nt] = __builtin_amdgcn_mfma_f32_16x16x32_bf16(a, b1, acc2[1][nt], 0, 0, 0);
        }
    }

    // (h2 + b2) . wkp, reduce within wave, then across waves
    float p0 = 0.f, p1 = 0.f;
    #pragma unroll
    for (int nt = 0; nt < 4; ++nt) {
        const int c0 = (w * 4 + nt) * 16 + lq * 4;
        const f32x4 b2 = *(const f32x4*)&bmu2[c0];
        const f32x4 wk = *(const f32x4*)&Wkp[c0];
        #pragma unroll
        for (int reg = 0; reg < 4; ++reg) {
            p0 = fmaf(acc2[0][nt][reg] + b2[reg], wk[reg], p0);
            p1 = fmaf(acc2[1][nt][reg] + b2[reg], wk[reg], p1);
        }
    }
    p0 += __shfl_xor(p0, 16, 64);  p0 += __shfl_xor(p0, 32, 64);
    p1 += __shfl_xor(p1, 16, 64);  p1 += __shfl_xor(p1, 32, 64);
    if (lane < 16) { red[w][0][lane] = p0; red[w][1][lane] = p1; }
    __syncthreads();

    if (t < 32) {
        const int mt = t >> 4, m = t & 15;
        const float s = red[0][mt][m] + red[1][mt][m] + red[2][mt][m] + red[3][mt][m];
        sh_shift[t] = 7.0f * (s + bkp[0]) + 2.0f;   // fold the +2 here
    }
    __syncthreads();

    // ---- adj fill: wave w owns rows w*8..w*8+7; exp only below icut ----
    #pragma unroll 2
    for (int rr = 0; rr < 8; ++rr) {
        const int r = w * 8 + rr;
        const float s = sh_shift[r];
        // exp needed only while s - 1792*i > -20  =>  i < (s+20)/1792
        const int icut = min(8, max(0, (int)ceilf((s + 20.0f) * (1.0f / 1792.0f))));
        float* adj = out + (size_t)(row0 + r) * NN;
        for (int i = 0; i < 8; ++i) {
            const int c = i * 256 + lane * 4;
            f32x4 a = {0.f, 0.f, 0.f, 0.f};
            if (i < icut) {                          // wave-uniform branch
                #pragma unroll
                for (int q = 0; q < 4; ++q) {
                    const float z = fmaf(-7.0f, (float)(c + q), s);
                    a[q] = 1.0f / (1.0f + __expf(-z));
                }
            }
            *(f32x4*)(adj + c) = a;
        }
    }
}

extern "C" void kernel_launch(void* const* d_in, const int* in_sizes, int n_in,
                              void* d_out, int out_size, void* d_ws, size_t ws_size,
                              hipStream_t stream)
{
    (void)in_sizes; (void)n_in; (void)out_size; (void)d_ws; (void)ws_size;
    const float* x    = (const float*)d_in[0];
    // d_in[1..5] dead: softmax over size-1 axis == 1 -> edge_prob == 1/N exactly;
    // stable argsort of all-ties rows == identity permutation.
    const float* Wmu1 = (const float*)d_in[6];
    const float* bmu1 = (const float*)d_in[7];
    const float* Wmu2 = (const float*)d_in[8];
    const float* bmu2 = (const float*)d_in[9];
    const float* Wkp  = (const float*)d_in[10];
    const float* bkp  = (const float*)d_in[11];

    hipLaunchKernelGGL(dgg_all, dim3(MLPB + 2048), dim3(256), 0, stream,
                       x, Wmu1, bmu1, Wmu2, bmu2, Wkp, bkp, (float*)d_out);
}